// Round 1
// baseline (142.526 us; speedup 1.0000x reference)
//
#include <hip/hip_runtime.h>

#define NS 32

// ---------------------------------------------------------------------------
// Kernel 1: ball query. Block = 256 threads = 4 waves, owns 64 query points
// (all in the same batch segment since n % 64 == 0). Wave w scans quarter w
// of the n candidates; per-quarter hit lists (ascending local idx, <= 32) go
// to LDS; merge phase takes the first 32 of the ordered concatenation and
// writes GLOBAL row indices to idx_out (the weight region of d_out).
// ---------------------------------------------------------------------------
__global__ __launch_bounds__(256) void bq_kernel(
    const float* __restrict__ xyz, const float* __restrict__ new_xyz,
    int n, int* __restrict__ idx_out)
{
#pragma clang fp contract(off)
    __shared__ unsigned short cand[64][4][NS];   // 16 KB
    __shared__ int scnt[64][4];                  // 1 KB

    const int tid  = threadIdx.x;
    const int ql   = tid & 63;                                   // query within block
    const int part = __builtin_amdgcn_readfirstlane(tid >> 6);   // wave id 0..3 (scalar)
    const int q0b  = blockIdx.x * 64;                            // first query of block
    const int base = (q0b / n) * n;                              // batch row base (scalar)
    const int q    = q0b + ql;

    const float qx = new_xyz[q * 3 + 0];
    const float qy = new_xyz[q * 3 + 1];
    const float qz = new_xyz[q * 3 + 2];

    const int seg = n >> 2;
    const int j0  = part * seg;
    const float* __restrict__ px = xyz + (size_t)(base + j0) * 3;

    int cnt = 0;
    unsigned short* my = &cand[ql][part][0];
    for (int j = 0; j < seg; ++j) {
        float dx = qx - px[j * 3 + 0];
        float dy = qy - px[j * 3 + 1];
        float dz = qz - px[j * 3 + 2];
        float d2 = (dx * dx + dy * dy) + dz * dz;   // contract(off): match numpy rounding
        if (d2 < 4.0f && cnt < NS) {                // RADIUS^2 = 4.0
            my[cnt] = (unsigned short)(j0 + j);
            ++cnt;
        }
    }
    scnt[ql][part] = cnt;
    __syncthreads();

    // Merge: 64 queries x 32 slots = 2048 assignments over 256 threads.
    for (int it = 0; it < 8; ++it) {
        int lin = (it << 8) + tid;
        int qq  = lin >> 5;
        int s   = lin & 31;
        int c0 = scnt[qq][0], c1 = scnt[qq][1], c2 = scnt[qq][2], c3 = scnt[qq][3];
        int t1 = c0 + c1, t2 = t1 + c2, t3 = t2 + c3;
        int j;
        if (s < c0)      j = cand[qq][0][s];
        else if (s < t1) j = cand[qq][1][s - c0];
        else if (s < t2) j = cand[qq][2][s - t1];
        else if (s < t3) j = cand[qq][3][s - t2];
        else {
            // pad with first found index; if none found, reference's idx=n
            // gather clamps to local row n-1.
            j = c0 ? cand[qq][0][0]
              : c1 ? cand[qq][1][0]
              : c2 ? cand[qq][2][0]
              : c3 ? cand[qq][3][0]
              : (n - 1);
        }
        idx_out[(q0b + qq) * NS + s] = base + j;   // global row index
    }
}

// ---------------------------------------------------------------------------
// Kernel 2: grouped relation. One float4 of samples per thread; writes both
// pred_local_relation and tgt_local_relation (shared idx loads).
// out layout: out[q*(C*NS) + c*NS + s].
// ---------------------------------------------------------------------------
template <int C>
__global__ __launch_bounds__(256) void group_kernel(
    const float* __restrict__ pred, const float* __restrict__ tgt,
    const int* __restrict__ idxb,
    float* __restrict__ out0, float* __restrict__ out1, int nelem4)
{
    int e = blockIdx.x * 256 + threadIdx.x;
    if (e >= nelem4) return;
    int q   = e / (C * (NS / 4));
    int rem = e - q * (C * (NS / 4));
    int c   = rem >> 3;        // NS/4 == 8
    int g   = rem & 7;

    int4 gi = *reinterpret_cast<const int4*>(idxb + q * NS + g * 4);
    float pc = pred[q * C + c];
    float tc = tgt[q * C + c];

    float4 p, t;
    p.x = pred[gi.x * C + c] - pc;
    p.y = pred[gi.y * C + c] - pc;
    p.z = pred[gi.z * C + c] - pc;
    p.w = pred[gi.w * C + c] - pc;
    t.x = tgt[gi.x * C + c] - tc;
    t.y = tgt[gi.y * C + c] - tc;
    t.z = tgt[gi.z * C + c] - tc;
    t.w = tgt[gi.w * C + c] - tc;

    reinterpret_cast<float4*>(out0)[e] = p;
    reinterpret_cast<float4*>(out1)[e] = t;
}

// ---------------------------------------------------------------------------
// Kernel 3: convert the idx rows (stored in the weight region) to weights,
// in place. Lane s of each 32-lane half-wave owns slot s of one query row.
// a[s] = (s==0 || idx[s]!=idx[0]); w = a / sum(a).
// ---------------------------------------------------------------------------
__global__ __launch_bounds__(256) void weight_kernel(float* __restrict__ w, int nelem)
{
    int e = blockIdx.x * 256 + threadIdx.x;
    if (e >= nelem) return;
    int lane = threadIdx.x & 63;
    int s    = e & 31;
    int idx  = reinterpret_cast<int*>(w)[e];
    int idx0 = __shfl(idx, lane & 32, 64);   // slot-0 value of this 32-lane group
    float a = (s == 0 || idx != idx0) ? 1.0f : 0.0f;
    float sum = a;
    #pragma unroll
    for (int off = 1; off < 32; off <<= 1)
        sum += __shfl_xor(sum, off, 64);     // masks <32 stay within the group
    w[e] = a / sum;
}

// ---------------------------------------------------------------------------
extern "C" void kernel_launch(void* const* d_in, const int* in_sizes, int n_in,
                              void* d_out, int out_size, void* d_ws, size_t ws_size,
                              hipStream_t stream)
{
    const float* xyz     = (const float*)d_in[0];
    const float* pred    = (const float*)d_in[2];
    const float* tgt     = (const float*)d_in[3];
    const float* new_xyz = (const float*)d_in[4];

    const int total = in_sizes[0] / 3;    // 16384
    const int nb    = in_sizes[1];        // 4
    const int n     = total / nb;         // 4096
    const int C     = in_sizes[2] / total; // 20

    float* out = (float*)d_out;
    const size_t relsz = (size_t)total * C * NS;
    float* out0 = out;
    float* out1 = out + relsz;
    // weight region doubles as idx scratch (exactly total*NS ints)
    int*   idxb = (int*)(out + 2 * relsz);

    bq_kernel<<<total / 64, 256, 0, stream>>>(xyz, new_xyz, n, idxb);

    const int nelem4  = total * C * (NS / 4);
    const int gblocks = (nelem4 + 255) / 256;
    if (C == 20) {
        group_kernel<20><<<gblocks, 256, 0, stream>>>(pred, tgt, idxb, out0, out1, nelem4);
    }

    const int welems = total * NS;
    weight_kernel<<<(welems + 255) / 256, 256, 0, stream>>>((float*)(out + 2 * relsz), welems);
}

// Round 2
// 58.567 us; speedup vs baseline: 2.4336x; 2.4336x over previous
//
#include <hip/hip_runtime.h>

#define NS 32

// ---------------------------------------------------------------------------
// Kernel 1: ball query. Block = 256 threads = 4 waves, owns 8 query points.
// The n candidates are split into 32 parts (seg = n/32); thread (q, p)
// scans part p for query q (lane layout: p = tid>>3, q = tid&7, so 8 lanes
// share each candidate address -> broadcast loads). Per-part hit lists
// (ascending local idx, capped at 32) go to LDS; merge phase takes the first
// 32 of the ordered concatenation and writes GLOBAL row indices to idx_out.
// Grid = total/8 = 2048 blocks -> 8 blocks/CU -> 32 waves/CU.
// ---------------------------------------------------------------------------
__global__ __launch_bounds__(256) void bq_kernel(
    const float* __restrict__ xyz, const float* __restrict__ new_xyz,
    int n, int* __restrict__ idx_out)
{
#pragma clang fp contract(off)
    __shared__ unsigned short cand[8][32][NS];   // 16 KB
    __shared__ int scnt[8][32];                  // 1 KB

    const int tid  = threadIdx.x;
    const int ql   = tid & 7;          // query within block
    const int p    = tid >> 3;         // part 0..31
    const int q0b  = blockIdx.x * 8;   // first query of block (n % 8 == 0)
    const int base = (q0b / n) * n;    // batch row base
    const int q    = q0b + ql;

    const float qx = new_xyz[q * 3 + 0];
    const float qy = new_xyz[q * 3 + 1];
    const float qz = new_xyz[q * 3 + 2];

    const int seg = (n + 31) >> 5;
    const int j0  = p * seg;
    const int lim = (n - j0 < seg) ? (n - j0) : seg;   // <= seg, may be <= 0
    const float4* __restrict__ px4 =
        reinterpret_cast<const float4*>(xyz + (size_t)(base + j0) * 3);

    int cnt = 0;
    unsigned short* my = &cand[ql][p][0];

    const int lim4 = (lim > 0 ? lim : 0) & ~3;
    #pragma unroll 2
    for (int j = 0; j < lim4; j += 4) {
        // 4 candidates = 12 consecutive floats = 3 aligned float4 loads
        float4 A = px4[(j >> 2) * 3 + 0];
        float4 B = px4[(j >> 2) * 3 + 1];
        float4 C = px4[(j >> 2) * 3 + 2];
        float xs[4] = {A.x, A.w, B.z, C.y};
        float ys[4] = {A.y, B.x, B.w, C.z};
        float zs[4] = {A.z, B.y, C.x, C.w};
        #pragma unroll
        for (int k = 0; k < 4; ++k) {
            float dx = qx - xs[k];
            float dy = qy - ys[k];
            float dz = qz - zs[k];
            float d2 = (dx * dx + dy * dy) + dz * dz;  // contract(off): numpy rounding
            if (d2 < 4.0f && cnt < NS) {               // RADIUS^2 = 4.0
                my[cnt] = (unsigned short)(j0 + j + k);
                ++cnt;
            }
        }
    }
    for (int j = lim4; j < lim; ++j) {                 // tail (n % 128 != 0 only)
        float dx = qx - xyz[(size_t)(base + j0 + j) * 3 + 0];
        float dy = qy - xyz[(size_t)(base + j0 + j) * 3 + 1];
        float dz = qz - xyz[(size_t)(base + j0 + j) * 3 + 2];
        float d2 = (dx * dx + dy * dy) + dz * dz;
        if (d2 < 4.0f && cnt < NS) {
            my[cnt] = (unsigned short)(j0 + j);
            ++cnt;
        }
    }
    scnt[ql][p] = cnt;
    __syncthreads();

    // Merge: 8 queries x 32 slots = 256 assignments, one per thread.
    const int qq = tid >> 5;
    const int s  = tid & 31;
    int acc = 0, jloc = -1, firstj = -1;
    #pragma unroll 1
    for (int pp = 0; pp < 32; ++pp) {
        int c = scnt[qq][pp];            // broadcast across the 32 lanes of qq
        if (c > 0) {
            if (firstj < 0) firstj = cand[qq][pp][0];
            if (jloc < 0 && s < acc + c) jloc = cand[qq][pp][s - acc];
            acc += c;
        }
    }
    if (jloc < 0)
        // pad with first found index; if none found, reference's idx=n gather
        // clamps to local row n-1.
        jloc = (firstj >= 0) ? firstj : (n - 1);
    idx_out[(q0b + qq) * NS + s] = base + jloc;   // global row index
}

// ---------------------------------------------------------------------------
// Kernel 2: grouped relation. One float4 of samples per thread; writes both
// pred_local_relation and tgt_local_relation (shared idx loads).
// out layout: out[q*(C*NS) + c*NS + s].
// ---------------------------------------------------------------------------
template <int C>
__global__ __launch_bounds__(256) void group_kernel(
    const float* __restrict__ pred, const float* __restrict__ tgt,
    const int* __restrict__ idxb,
    float* __restrict__ out0, float* __restrict__ out1, int nelem4)
{
    int e = blockIdx.x * 256 + threadIdx.x;
    if (e >= nelem4) return;
    int q   = e / (C * (NS / 4));
    int rem = e - q * (C * (NS / 4));
    int c   = rem >> 3;        // NS/4 == 8
    int g   = rem & 7;

    int4 gi = *reinterpret_cast<const int4*>(idxb + q * NS + g * 4);
    float pc = pred[q * C + c];
    float tc = tgt[q * C + c];

    float4 p, t;
    p.x = pred[gi.x * C + c] - pc;
    p.y = pred[gi.y * C + c] - pc;
    p.z = pred[gi.z * C + c] - pc;
    p.w = pred[gi.w * C + c] - pc;
    t.x = tgt[gi.x * C + c] - tc;
    t.y = tgt[gi.y * C + c] - tc;
    t.z = tgt[gi.z * C + c] - tc;
    t.w = tgt[gi.w * C + c] - tc;

    reinterpret_cast<float4*>(out0)[e] = p;
    reinterpret_cast<float4*>(out1)[e] = t;
}

// ---------------------------------------------------------------------------
// Kernel 3: convert the idx rows (stored in the weight region) to weights,
// in place. Lane s of each 32-lane half-wave owns slot s of one query row.
// a[s] = (s==0 || idx[s]!=idx[0]); w = a / sum(a).
// ---------------------------------------------------------------------------
__global__ __launch_bounds__(256) void weight_kernel(float* __restrict__ w, int nelem)
{
    int e = blockIdx.x * 256 + threadIdx.x;
    if (e >= nelem) return;
    int lane = threadIdx.x & 63;
    int s    = e & 31;
    int idx  = reinterpret_cast<int*>(w)[e];
    int idx0 = __shfl(idx, lane & 32, 64);   // slot-0 value of this 32-lane group
    float a = (s == 0 || idx != idx0) ? 1.0f : 0.0f;
    float sum = a;
    #pragma unroll
    for (int off = 1; off < 32; off <<= 1)
        sum += __shfl_xor(sum, off, 64);     // masks <32 stay within the group
    w[e] = a / sum;
}

// ---------------------------------------------------------------------------
extern "C" void kernel_launch(void* const* d_in, const int* in_sizes, int n_in,
                              void* d_out, int out_size, void* d_ws, size_t ws_size,
                              hipStream_t stream)
{
    const float* xyz     = (const float*)d_in[0];
    const float* pred    = (const float*)d_in[2];
    const float* tgt     = (const float*)d_in[3];
    const float* new_xyz = (const float*)d_in[4];

    const int total = in_sizes[0] / 3;     // 16384
    const int nb    = in_sizes[1];         // 4
    const int n     = total / nb;          // 4096
    const int C     = in_sizes[2] / total; // 20

    float* out = (float*)d_out;
    const size_t relsz = (size_t)total * C * NS;
    float* out0 = out;
    float* out1 = out + relsz;
    // weight region doubles as idx scratch (exactly total*NS ints)
    int*   idxb = (int*)(out + 2 * relsz);

    bq_kernel<<<total / 8, 256, 0, stream>>>(xyz, new_xyz, n, idxb);

    const int nelem4  = total * C * (NS / 4);
    const int gblocks = (nelem4 + 255) / 256;
    if (C == 20) {
        group_kernel<20><<<gblocks, 256, 0, stream>>>(pred, tgt, idxb, out0, out1, nelem4);
    }

    const int welems = total * NS;
    weight_kernel<<<(welems + 255) / 256, 256, 0, stream>>>((float*)(out + 2 * relsz), welems);
}

// Round 3
// 48.443 us; speedup vs baseline: 2.9421x; 1.2090x over previous
//
#include <hip/hip_runtime.h>

#define NS 32

// ---------------------------------------------------------------------------
// Fused kernel: ball query (ballot compaction) + weight + grouped relation.
//
// One wave owns 2 consecutive queries (same batch segment; n is even).
// Scan: per iteration, 128 candidates in two 64-chunks. Per chunk & query:
//   d2 < r^2 -> ballot -> (rare, ~24%) scalar branch: prefix via mbcnt gives
//   the compacted slot; hits land in the wave's 32-int LDS row in ascending
//   index order (matches reference top_k-on-index semantics). Pad with first
//   hit (n-1 if none, matching the reference's clamped gather of idx==n).
// Weight: real hits are distinct ascending indices and pads equal idx[0],
//   so a[s] = (s < tc) and w = a / max(tc,1). No reread of idx needed.
// Group: lane (qs, s) gathers neighbor row (5x float4, rows are 80 B and
//   16B-aligned), subtracts center row, stores coalesced (32 contiguous
//   dwords per half-wave) to out[q][c][s].
// Grid: total/8 blocks x 256 -> 2048 blocks, 8/CU, LDS 1 KB/block.
// ---------------------------------------------------------------------------
template <int C>
__global__ __launch_bounds__(256) void fused_kernel(
    const float* __restrict__ xyz, const float* __restrict__ new_xyz,
    const float* __restrict__ pred, const float* __restrict__ tgt,
    int n, int total, float* __restrict__ out0, float* __restrict__ out1,
    float* __restrict__ wout)
{
#pragma clang fp contract(off)
    __shared__ int sidx[8][NS];   // 8 queries per block

    const int lane = threadIdx.x & 63;
    const int wv   = __builtin_amdgcn_readfirstlane(threadIdx.x >> 6);  // 0..3
    int q0 = (blockIdx.x * 4 + wv) * 2;          // first of this wave's 2 queries
    if (q0 > total - 2) q0 = total - 2;          // safety clamp (total % 8 == 0 normally)
    const int base = (q0 / n) * n;               // batch row base

    const float ax0 = new_xyz[q0 * 3 + 0], ay0 = new_xyz[q0 * 3 + 1], az0 = new_xyz[q0 * 3 + 2];
    const float ax1 = new_xyz[q0 * 3 + 3], ay1 = new_xyz[q0 * 3 + 4], az1 = new_xyz[q0 * 3 + 5];

    const float* __restrict__ px = xyz + (size_t)base * 3;

    int tot0 = 0, tot1 = 0;
    int first0 = n - 1, first1 = n - 1;   // local idx; n-1 = clamp of ref's idx==n

    for (int it = 0; it < n; it += 128) {
        const int ja = it + lane;
        const int jb = ja + 64;
        const int jca = ja < n ? ja : n - 1;   // clamped load (n % 128 != 0 only)
        const int jcb = jb < n ? jb : n - 1;
        const float xa = px[jca * 3 + 0], ya = px[jca * 3 + 1], za = px[jca * 3 + 2];
        const float xb = px[jcb * 3 + 0], yb = px[jcb * 3 + 1], zb = px[jcb * 3 + 2];

        // ---- chunk A: candidates [it, it+64) ----
        {
            float dx = ax0 - xa, dy = ay0 - ya, dz = az0 - za;
            const float d0 = (dx * dx + dy * dy) + dz * dz;   // contract(off): numpy rounding
            dx = ax1 - xa; dy = ay1 - ya; dz = az1 - za;
            const float d1 = (dx * dx + dy * dy) + dz * dz;
            const bool h0 = (ja < n) & (d0 < 4.0f);
            const bool h1 = (ja < n) & (d1 < 4.0f);
            const unsigned long long m0 = __ballot(h0);
            if (m0) {
                if (tot0 == 0) first0 = it + __builtin_ctzll(m0);
                const int pos = tot0 + __builtin_amdgcn_mbcnt_hi(
                    (unsigned)(m0 >> 32), __builtin_amdgcn_mbcnt_lo((unsigned)m0, 0u));
                if (h0 && pos < NS) sidx[wv * 2 + 0][pos] = ja;
                tot0 += __popcll(m0);
            }
            const unsigned long long m1 = __ballot(h1);
            if (m1) {
                if (tot1 == 0) first1 = it + __builtin_ctzll(m1);
                const int pos = tot1 + __builtin_amdgcn_mbcnt_hi(
                    (unsigned)(m1 >> 32), __builtin_amdgcn_mbcnt_lo((unsigned)m1, 0u));
                if (h1 && pos < NS) sidx[wv * 2 + 1][pos] = ja;
                tot1 += __popcll(m1);
            }
        }
        // ---- chunk B: candidates [it+64, it+128) ----
        {
            float dx = ax0 - xb, dy = ay0 - yb, dz = az0 - zb;
            const float d0 = (dx * dx + dy * dy) + dz * dz;
            dx = ax1 - xb; dy = ay1 - yb; dz = az1 - zb;
            const float d1 = (dx * dx + dy * dy) + dz * dz;
            const bool h0 = (jb < n) & (d0 < 4.0f);
            const bool h1 = (jb < n) & (d1 < 4.0f);
            const unsigned long long m0 = __ballot(h0);
            if (m0) {
                if (tot0 == 0) first0 = it + 64 + __builtin_ctzll(m0);
                const int pos = tot0 + __builtin_amdgcn_mbcnt_hi(
                    (unsigned)(m0 >> 32), __builtin_amdgcn_mbcnt_lo((unsigned)m0, 0u));
                if (h0 && pos < NS) sidx[wv * 2 + 0][pos] = jb;
                tot0 += __popcll(m0);
            }
            const unsigned long long m1 = __ballot(h1);
            if (m1) {
                if (tot1 == 0) first1 = it + 64 + __builtin_ctzll(m1);
                const int pos = tot1 + __builtin_amdgcn_mbcnt_hi(
                    (unsigned)(m1 >> 32), __builtin_amdgcn_mbcnt_lo((unsigned)m1, 0u));
                if (h1 && pos < NS) sidx[wv * 2 + 1][pos] = jb;
                tot1 += __popcll(m1);
            }
        }
        if (tot0 >= NS && tot1 >= NS) break;   // uniform, rare
    }

    // ---- pad LDS row + write weights ----
    const int s  = lane & 31;
    const int qs = lane >> 5;
    {
        const int tot   = qs ? tot1 : tot0;
        const int first = qs ? first1 : first0;
        const int tc    = tot < NS ? tot : NS;
        if (s >= tc) sidx[wv * 2 + qs][s] = first;
        const int tcm = tc > 0 ? tc : 1;
        // lane 0..63 covers both queries' contiguous weight rows
        wout[(size_t)q0 * NS + lane] = (s < tcm) ? 1.0f / (float)tcm : 0.0f;
    }
    __syncthreads();   // LDS visibility (intra-wave exchange)

    // ---- grouped relation ----
    {
        const int q  = q0 + qs;
        const int jl = sidx[wv * 2 + qs][s];
        const float4* __restrict__ nb_p = (const float4*)(pred + (size_t)(base + jl) * C);
        const float4* __restrict__ nb_t = (const float4*)(tgt  + (size_t)(base + jl) * C);
        const float4* __restrict__ ct_p = (const float4*)(pred + (size_t)q * C);
        const float4* __restrict__ ct_t = (const float4*)(tgt  + (size_t)q * C);
        float* __restrict__ o0 = out0 + (size_t)q * (C * NS) + s;
        float* __restrict__ o1 = out1 + (size_t)q * (C * NS) + s;
        #pragma unroll
        for (int c4 = 0; c4 < C / 4; ++c4) {
            const float4 a = nb_p[c4], b = ct_p[c4];
            o0[(c4 * 4 + 0) * NS] = a.x - b.x;
            o0[(c4 * 4 + 1) * NS] = a.y - b.y;
            o0[(c4 * 4 + 2) * NS] = a.z - b.z;
            o0[(c4 * 4 + 3) * NS] = a.w - b.w;
            const float4 u = nb_t[c4], v = ct_t[c4];
            o1[(c4 * 4 + 0) * NS] = u.x - v.x;
            o1[(c4 * 4 + 1) * NS] = u.y - v.y;
            o1[(c4 * 4 + 2) * NS] = u.z - v.z;
            o1[(c4 * 4 + 3) * NS] = u.w - v.w;
        }
        #pragma unroll
        for (int c = (C / 4) * 4; c < C; ++c) {   // tail if C % 4 != 0 (dead for C=20)
            o0[c * NS] = pred[(size_t)(base + jl) * C + c] - pred[(size_t)q * C + c];
            o1[c * NS] = tgt [(size_t)(base + jl) * C + c] - tgt [(size_t)q * C + c];
        }
    }
}

// ---------------------------------------------------------------------------
extern "C" void kernel_launch(void* const* d_in, const int* in_sizes, int n_in,
                              void* d_out, int out_size, void* d_ws, size_t ws_size,
                              hipStream_t stream)
{
    const float* xyz     = (const float*)d_in[0];
    const float* pred    = (const float*)d_in[2];
    const float* tgt     = (const float*)d_in[3];
    const float* new_xyz = (const float*)d_in[4];

    const int total = in_sizes[0] / 3;     // 16384
    const int nb    = in_sizes[1];         // 4
    const int n     = total / nb;          // 4096
    const int C     = in_sizes[2] / total; // 20

    float* out = (float*)d_out;
    const size_t relsz = (size_t)total * C * NS;
    float* out0 = out;
    float* out1 = out + relsz;
    float* wout = out + 2 * relsz;

    const int blocks = (total + 7) / 8;    // 2 queries/wave, 4 waves/block
    if (C == 20) {
        fused_kernel<20><<<blocks, 256, 0, stream>>>(
            xyz, new_xyz, pred, tgt, n, total, out0, out1, wout);
    }
    (void)d_ws; (void)ws_size; (void)n_in; (void)out_size;
}

// Round 4
// 41.611 us; speedup vs baseline: 3.4252x; 1.1642x over previous
//
#include <hip/hip_runtime.h>

#define NS 32
#define GX 10
#define GY 10
#define NCELL (GX * GY)
#define CAP 96
#define INV_CELL 0.5f
#define MARGIN 1e-3f

// ---------------------------------------------------------------------------
// K0: zero the per-cell counters (re-zeroed every call: deterministic).
// ---------------------------------------------------------------------------
__global__ void zero_kernel(int* __restrict__ cnt, int ntot)
{
    int i = blockIdx.x * 256 + threadIdx.x;
    if (i < ntot) cnt[i] = 0;
}

// ---------------------------------------------------------------------------
// K1: count + scatter points into capped per-(batch,cell) lists.
// Cell grid is (x,y) only, 10x10 of size 2.0 over the 20^3 cube. Each entry
// stores (x,y,z, local_idx bitcast). Within-cell order is nondeterministic
// (atomics) but the query kernel sorts hits by index, so outputs are
// deterministic.
// ---------------------------------------------------------------------------
__global__ __launch_bounds__(256) void bin_kernel(
    const float* __restrict__ xyz, int n, int total,
    int* __restrict__ cnt, float4* __restrict__ cellpts)
{
    int i = blockIdx.x * 256 + threadIdx.x;
    if (i >= total) return;
    int b  = i / n;
    int il = i - b * n;
    float x = xyz[3 * i + 0], y = xyz[3 * i + 1], z = xyz[3 * i + 2];
    int cx = (int)floorf(x * INV_CELL); cx = min(max(cx, 0), GX - 1);
    int cy = (int)floorf(y * INV_CELL); cy = min(max(cy, 0), GY - 1);
    int cell = b * NCELL + cx * GY + cy;
    int pos = atomicAdd(&cnt[cell], 1);
    if (pos < CAP)
        cellpts[(size_t)cell * CAP + pos] = make_float4(x, y, z, __int_as_float(il));
}

// ---------------------------------------------------------------------------
// K2: fused query + weight + grouped relation. One wave per query.
// Scan the <=9 neighbor cells' capped lists (~370 candidates), ballot-compact
// hit local-indices into a 64-entry LDS list, bitonic-sort ascending across
// the wave (reference semantics: first 32 by index, pad with first; n-1 if
// none). Lanes 0-31 then emit pred relation + weights, lanes 32-63 tgt.
// ---------------------------------------------------------------------------
template <int C>
__global__ __launch_bounds__(256) void query_kernel(
    const float* __restrict__ new_xyz,
    const float* __restrict__ pred, const float* __restrict__ tgt,
    const int* __restrict__ cnt, const float4* __restrict__ cellpts,
    int n, int total,
    float* __restrict__ out0, float* __restrict__ out1, float* __restrict__ wout)
{
#pragma clang fp contract(off)
    __shared__ int slist[4][64];

    const int lane = threadIdx.x & 63;
    const int wv   = __builtin_amdgcn_readfirstlane(threadIdx.x >> 6);
    const int q    = blockIdx.x * 4 + wv;
    if (q >= total) return;
    const int b    = q / n;
    const int base = b * n;

    const float qx = new_xyz[q * 3 + 0];
    const float qy = new_xyz[q * 3 + 1];
    const float qz = new_xyz[q * 3 + 2];

    // cell range with margin so boundary rounding can never drop a true hit
    int cx0 = (int)floorf((qx - 2.0f - MARGIN) * INV_CELL); cx0 = max(cx0, 0);
    int cx1 = (int)floorf((qx + 2.0f + MARGIN) * INV_CELL); cx1 = min(cx1, GX - 1);
    int cy0 = (int)floorf((qy - 2.0f - MARGIN) * INV_CELL); cy0 = max(cy0, 0);
    int cy1 = (int)floorf((qy + 2.0f + MARGIN) * INV_CELL); cy1 = min(cy1, GY - 1);

    int tot = 0;
    const int bb = b * NCELL;
    for (int cx = cx0; cx <= cx1; ++cx) {
        for (int cy = cy0; cy <= cy1; ++cy) {
            const int cell = bb + cx * GY + cy;
            int cc = cnt[cell]; cc = cc < CAP ? cc : CAP;
            const float4* __restrict__ pl = cellpts + (size_t)cell * CAP;
            for (int r = 0; r < cc; r += 64) {
                const int  t   = r + lane;
                const bool act = t < cc;
                const float4 f = pl[act ? t : 0];
                float dx = qx - f.x, dy = qy - f.y, dz = qz - f.z;
                float d2 = (dx * dx + dy * dy) + dz * dz;   // numpy rounding order
                const bool hit = act && (d2 < 4.0f);        // RADIUS^2
                const unsigned long long m = __ballot(hit);
                const int pos = tot + __builtin_amdgcn_mbcnt_hi(
                    (unsigned)(m >> 32), __builtin_amdgcn_mbcnt_lo((unsigned)m, 0u));
                if (hit && pos < 64) slist[wv][pos] = __float_as_int(f.w);
                tot += __popcll(m);
            }
        }
    }

    // sort hit indices ascending across the wave (pad INT_MAX)
    int v = (lane < tot) ? slist[wv][lane] : 0x7fffffff;
    #pragma unroll
    for (int k = 2; k <= 64; k <<= 1) {
        #pragma unroll
        for (int j = k >> 1; j >= 1; j >>= 1) {
            const int  o     = __shfl_xor(v, j, 64);
            const bool up    = ((lane & k) == 0);
            const bool lower = ((lane & j) == 0);
            const int  mn = v < o ? v : o;
            const int  mx = v < o ? o : v;
            v = (lower == up) ? mn : mx;
        }
    }

    const int tc    = tot < NS ? tot : NS;
    const int firstv = __shfl(v, 0, 64);
    const int first = (tot > 0) ? firstv : (n - 1);   // ref: idx==n gather clamps
    const int s     = lane & 31;
    const int jl0   = __shfl(v, s, 64);
    const int jl    = (s < tc) ? jl0 : first;

    // weights (lanes 0-31 cover the query's 32 slots)
    const int tcm = tc > 0 ? tc : 1;
    if (lane < NS)
        wout[(size_t)q * NS + lane] = (lane < tcm) ? 1.0f / (float)tcm : 0.0f;

    // grouped relation: half-wave 0 -> pred/out0, half-wave 1 -> tgt/out1
    const float* __restrict__ src = (lane >> 5) ? tgt : pred;
    float* __restrict__ dst       = (lane >> 5) ? out1 : out0;
    const float4* __restrict__ nb = (const float4*)(src + (size_t)(base + jl) * C);
    const float4* __restrict__ ct = (const float4*)(src + (size_t)q * C);
    float* __restrict__ o = dst + (size_t)q * (C * NS) + s;
    #pragma unroll
    for (int c4 = 0; c4 < C / 4; ++c4) {
        const float4 a = nb[c4], bq = ct[c4];
        o[(c4 * 4 + 0) * NS] = a.x - bq.x;
        o[(c4 * 4 + 1) * NS] = a.y - bq.y;
        o[(c4 * 4 + 2) * NS] = a.z - bq.z;
        o[(c4 * 4 + 3) * NS] = a.w - bq.w;
    }
    #pragma unroll
    for (int c = (C / 4) * 4; c < C; ++c)   // dead for C=20
        o[c * NS] = src[(size_t)(base + jl) * C + c] - src[(size_t)q * C + c];
}

// ---------------------------------------------------------------------------
// Fallback: the round-3 fused brute-force kernel (used if ws_size too small).
// ---------------------------------------------------------------------------
template <int C>
__global__ __launch_bounds__(256) void fused_brute_kernel(
    const float* __restrict__ xyz, const float* __restrict__ new_xyz,
    const float* __restrict__ pred, const float* __restrict__ tgt,
    int n, int total, float* __restrict__ out0, float* __restrict__ out1,
    float* __restrict__ wout)
{
#pragma clang fp contract(off)
    __shared__ int sidx[8][NS];

    const int lane = threadIdx.x & 63;
    const int wv   = __builtin_amdgcn_readfirstlane(threadIdx.x >> 6);
    int q0 = (blockIdx.x * 4 + wv) * 2;
    if (q0 > total - 2) q0 = total - 2;
    const int base = (q0 / n) * n;

    const float ax0 = new_xyz[q0 * 3 + 0], ay0 = new_xyz[q0 * 3 + 1], az0 = new_xyz[q0 * 3 + 2];
    const float ax1 = new_xyz[q0 * 3 + 3], ay1 = new_xyz[q0 * 3 + 4], az1 = new_xyz[q0 * 3 + 5];
    const float* __restrict__ px = xyz + (size_t)base * 3;

    int tot0 = 0, tot1 = 0, first0 = n - 1, first1 = n - 1;
    for (int it = 0; it < n; it += 64) {
        const int ja  = it + lane;
        const int jca = ja < n ? ja : n - 1;
        const float xa = px[jca * 3 + 0], ya = px[jca * 3 + 1], za = px[jca * 3 + 2];
        float dx = ax0 - xa, dy = ay0 - ya, dz = az0 - za;
        const float d0 = (dx * dx + dy * dy) + dz * dz;
        dx = ax1 - xa; dy = ay1 - ya; dz = az1 - za;
        const float d1 = (dx * dx + dy * dy) + dz * dz;
        const bool h0 = (ja < n) & (d0 < 4.0f);
        const bool h1 = (ja < n) & (d1 < 4.0f);
        const unsigned long long m0 = __ballot(h0);
        if (m0) {
            if (tot0 == 0) first0 = it + __builtin_ctzll(m0);
            const int pos = tot0 + __builtin_amdgcn_mbcnt_hi(
                (unsigned)(m0 >> 32), __builtin_amdgcn_mbcnt_lo((unsigned)m0, 0u));
            if (h0 && pos < NS) sidx[wv * 2 + 0][pos] = ja;
            tot0 += __popcll(m0);
        }
        const unsigned long long m1 = __ballot(h1);
        if (m1) {
            if (tot1 == 0) first1 = it + __builtin_ctzll(m1);
            const int pos = tot1 + __builtin_amdgcn_mbcnt_hi(
                (unsigned)(m1 >> 32), __builtin_amdgcn_mbcnt_lo((unsigned)m1, 0u));
            if (h1 && pos < NS) sidx[wv * 2 + 1][pos] = ja;
            tot1 += __popcll(m1);
        }
    }

    const int s  = lane & 31;
    const int qs = lane >> 5;
    {
        const int tt    = qs ? tot1 : tot0;
        const int first = qs ? first1 : first0;
        const int tc    = tt < NS ? tt : NS;
        if (s >= tc) sidx[wv * 2 + qs][s] = first;
        const int tcm = tc > 0 ? tc : 1;
        wout[(size_t)q0 * NS + lane] = (s < tcm) ? 1.0f / (float)tcm : 0.0f;
    }
    __syncthreads();

    const int q  = q0 + qs;
    const int jl = sidx[wv * 2 + qs][s];
    const float4* __restrict__ nb_p = (const float4*)(pred + (size_t)(base + jl) * C);
    const float4* __restrict__ nb_t = (const float4*)(tgt  + (size_t)(base + jl) * C);
    const float4* __restrict__ ct_p = (const float4*)(pred + (size_t)q * C);
    const float4* __restrict__ ct_t = (const float4*)(tgt  + (size_t)q * C);
    float* __restrict__ o0 = out0 + (size_t)q * (C * NS) + s;
    float* __restrict__ o1 = out1 + (size_t)q * (C * NS) + s;
    #pragma unroll
    for (int c4 = 0; c4 < C / 4; ++c4) {
        const float4 a = nb_p[c4], bq = ct_p[c4];
        o0[(c4 * 4 + 0) * NS] = a.x - bq.x;
        o0[(c4 * 4 + 1) * NS] = a.y - bq.y;
        o0[(c4 * 4 + 2) * NS] = a.z - bq.z;
        o0[(c4 * 4 + 3) * NS] = a.w - bq.w;
        const float4 u = nb_t[c4], vv = ct_t[c4];
        o1[(c4 * 4 + 0) * NS] = u.x - vv.x;
        o1[(c4 * 4 + 1) * NS] = u.y - vv.y;
        o1[(c4 * 4 + 2) * NS] = u.z - vv.z;
        o1[(c4 * 4 + 3) * NS] = u.w - vv.w;
    }
}

// ---------------------------------------------------------------------------
extern "C" void kernel_launch(void* const* d_in, const int* in_sizes, int n_in,
                              void* d_out, int out_size, void* d_ws, size_t ws_size,
                              hipStream_t stream)
{
    const float* xyz     = (const float*)d_in[0];
    const float* pred    = (const float*)d_in[2];
    const float* tgt     = (const float*)d_in[3];
    const float* new_xyz = (const float*)d_in[4];

    const int total = in_sizes[0] / 3;     // 16384
    const int nb    = in_sizes[1];         // 4
    const int n     = total / nb;          // 4096
    const int C     = in_sizes[2] / total; // 20

    float* out = (float*)d_out;
    const size_t relsz = (size_t)total * C * NS;
    float* out0 = out;
    float* out1 = out + relsz;
    float* wout = out + 2 * relsz;

    const int ncells = nb * NCELL;
    const size_t ws_need = (size_t)ncells * CAP * sizeof(float4) + (size_t)ncells * sizeof(int);

    if (C == 20 && ws_size >= ws_need) {
        float4* cellpts = (float4*)d_ws;                       // 16B-aligned base
        int*    cnt     = (int*)((char*)d_ws + (size_t)ncells * CAP * sizeof(float4));

        zero_kernel<<<(ncells + 255) / 256, 256, 0, stream>>>(cnt, ncells);
        bin_kernel<<<(total + 255) / 256, 256, 0, stream>>>(xyz, n, total, cnt, cellpts);
        query_kernel<20><<<(total + 3) / 4, 256, 0, stream>>>(
            new_xyz, pred, tgt, cnt, cellpts, n, total, out0, out1, wout);
    } else if (C == 20) {
        fused_brute_kernel<20><<<(total + 7) / 8, 256, 0, stream>>>(
            xyz, new_xyz, pred, tgt, n, total, out0, out1, wout);
    }
    (void)n_in; (void)out_size;
}